// Round 11
// baseline (83.063 us; speedup 1.0000x reference)
//
#include <hip/hip_runtime.h>
#include <hip/hip_bf16.h>

#define NFFT    512
#define HOPSZ   128
#define FBINS   257
#define TFR     2048
#define NBC     32            // B*C
#define OUTLEN  262016        // (T-1)*HOP
#define SPAD    256           // n_fft/2 (center trim)

typedef __bf16 bf16x8 __attribute__((ext_vector_type(8)));
typedef float  f32x4  __attribute__((ext_vector_type(4)));

static __device__ __forceinline__ float bf2f(unsigned short u) {
    union { unsigned int i; float f; } x; x.i = (unsigned int)u << 16; return x.f;
}

__device__ __forceinline__ void gld_lds16(const void* g, void* l) {
    __builtin_amdgcn_global_load_lds(
        (const __attribute__((address_space(1))) unsigned int*)g,
        (__attribute__((address_space(3))) unsigned int*)l, 16, 0, 0);
}

// ---------------------------------------------------------------------------
// Kernel 1: W' in MFMA A-fragment order (verified R2-R10).
//   Wf[(ks*32 + rt)*64 + lane]: 8 bf16, elem j:
//     n = rt*16 + (lane&15),  k = ks*32 + 4*(lane>>4) + (j&3) + 16*(j>>2)
// ---------------------------------------------------------------------------
__global__ __launch_bounds__(256) void k_wgen(const float* __restrict__ wnd,
                                              uint4* __restrict__ Wf) {
    const int gid  = blockIdx.x * 256 + threadIdx.x;   // < 34816
    const int lane = gid & 63;
    const int rt   = (gid >> 6) & 31;
    const int ks   = gid >> 11;
    const int n    = rt * 16 + (lane & 15);
    const int kb   = ks * 32 + ((lane >> 4) << 2);
    const float wn = wnd[n] * (1.0f / 512.0f);
    union { uint4 u; unsigned short h[8]; } o;
    #pragma unroll
    for (int j = 0; j < 8; ++j) {
        const int k = kb + (j & 3) + 16 * (j >> 2);
        float val = 0.0f;
        if (k < 2 * FBINS) {
            const int f = k >> 1;
            const bool edge = (f == 0) || (f == 256);
            const float cf = edge ? 1.0f : 2.0f;
            const int m = (f * n) & (NFFT - 1);
            const float ang = (float)m * 0.01227184630308513f; // 2*pi/512
            float s, c;
            __sincosf(ang, &s, &c);
            val = (k & 1) ? (edge ? 0.0f : -cf * wn * s) : (cf * wn * c);
        }
        __hip_bfloat16 hb = __float2bfloat16(val);
        o.h[j] = *(unsigned short*)&hb;
    }
    Wf[gid] = o.u;
}

// ---------------------------------------------------------------------------
// Kernel 2: frames(k<512) = W'[:, :512] @ X.
//   DMA-SUPPLY FIX: global_load_lds supply ~22 B/cy/CU (m97-derived) bound
//   every prior round (R10: 768 MB staged -> 57 us). Now ONLY B flows
//   through the DMA (8 KB/period; 256 MB chip-wide -> ~20 us floor).
//   A is streamed from L2 (Wf = 512 KB, resident) straight into REGISTERS,
//   double-buffered one period ahead; its ~200 cy L2 latency hides under
//   B's DMA drain. LDS reads are B-only (A never in LDS) -> 0 conflicts.
//   Macro-shape/indexing identical to R10 (verified): 2048 blocks x 4 waves,
//   rows [256m,+256) (wave w: 64 rows), 64-t panel, single-buffered period.
// ---------------------------------------------------------------------------
__global__ __launch_bounds__(256, 3) void k_mm(
    const float* __restrict__ X,
    const uint4* __restrict__ Wf,
    __hip_bfloat16* __restrict__ frames)
{
    __shared__ float2 Bf[16][64];     // 8 KB: [f_local][t] raw fp32

    const int tid  = threadIdx.x;
    const int lane = tid & 63;
    const int w    = tid >> 6;        // wave 0..3 -> rows [64w,+64)
    const int q    = lane >> 4;
    const int rlo  = lane & 15;

    const int bid = blockIdx.x;       // 2048 = 8 XCD-chunks of 256
    const int id  = (bid & 7) * 256 + (bid >> 3);
    const int m     = id & 1;         // M-half: rows [256m,+256)
    const int panel = (id >> 1) & 31; // 64-t panel
    const int bc    = id >> 6;        // 0..31
    const int t0b   = panel << 6;

    const float2* __restrict__ X2 = (const float2*)X + (size_t)bc * FBINS * TFR;

    // B staging roles (R10-verified: wave-uniform base + 16*lane)
    const int br  = tid >> 5;         // B row 0..7 (also +8)
    const int bck = tid & 31;         // 16B chunk within row

    f32x4 acc[4][4] = {};
    uint4 arA[4], arB[4];

    auto loadA = [&](int ks, uint4 (&ar)[4]) {     // 4x coalesced uint4, L2-hot
        const uint4* ap = Wf + (size_t)ks * 2048 + m * 1024 + (4 * w) * 64 + lane;
        ar[0] = ap[0];
        ar[1] = ap[64];
        ar[2] = ap[128];
        ar[3] = ap[192];
    };
    auto stageB = [&](int ks) {                    // 2x gld_lds (8 KB total)
        const float2* b0 = X2 + (size_t)(ks * 16 + br) * TFR + t0b + 2 * bck;
        gld_lds16(b0,                   &Bf[br][2 * bck]);
        gld_lds16(b0 + (size_t)8 * TFR, &Bf[br + 8][2 * bck]);
    };
    auto computeP = [&](uint4 (&ar)[4]) {          // 16 MFMA / wave
        uint4 b[4];
        #pragma unroll
        for (int ni = 0; ni < 4; ++ni) {
            const float2* Bp = &Bf[2 * q][ni * 16 + rlo];
            float2 v0 = Bp[0];
            float2 v1 = Bp[64];       // f = 2q+1
            float2 v2 = Bp[8 * 64];   // f = 2q+8
            float2 v3 = Bp[9 * 64];   // f = 2q+9
            union { unsigned short h[8]; uint4 u; } pk;
            __hip_bfloat16 t;
            t = __float2bfloat16(v0.x); pk.h[0] = *(unsigned short*)&t;
            t = __float2bfloat16(v0.y); pk.h[1] = *(unsigned short*)&t;
            t = __float2bfloat16(v1.x); pk.h[2] = *(unsigned short*)&t;
            t = __float2bfloat16(v1.y); pk.h[3] = *(unsigned short*)&t;
            t = __float2bfloat16(v2.x); pk.h[4] = *(unsigned short*)&t;
            t = __float2bfloat16(v2.y); pk.h[5] = *(unsigned short*)&t;
            t = __float2bfloat16(v3.x); pk.h[6] = *(unsigned short*)&t;
            t = __float2bfloat16(v3.y); pk.h[7] = *(unsigned short*)&t;
            b[ni] = pk.u;
        }
        #pragma unroll
        for (int mi = 0; mi < 4; ++mi)
            #pragma unroll
            for (int ni = 0; ni < 4; ++ni)
                acc[mi][ni] = __builtin_amdgcn_mfma_f32_16x16x32_bf16(
                    __builtin_bit_cast(bf16x8, ar[mi]),
                    __builtin_bit_cast(bf16x8, b[ni]), acc[mi][ni], 0, 0, 0);
    };

    loadA(0, arA);
    #pragma unroll
    for (int kp = 0; kp < 8; ++kp) {
        // even period ks = 2kp: cur = arA, prefetch -> arB
        __syncthreads();              // Bf free (prev compute drained own reads)
        stageB(2 * kp);
        loadA(2 * kp + 1, arB);       // L2 latency hides under B's DMA drain
        __syncthreads();              // drains DMA (+ A-next, already landed)
        computeP(arA);
        // odd period ks = 2kp+1: cur = arB, prefetch -> arA
        __syncthreads();
        stageB(2 * kp + 1);
        if (kp < 7) loadA(2 * kp + 2, arA);
        __syncthreads();
        computeP(arB);
    }

    // epilogue: C/D row=(l>>4)*4+reg -> n, col=l&15 -> t (verified R1-R10)
    unsigned short* fb = (unsigned short*)frames;
    #pragma unroll
    for (int mi = 0; mi < 4; ++mi) {
        const int nbase = m * 256 + (w << 6) + (mi << 4) + (q << 2);
        #pragma unroll
        for (int ni = 0; ni < 4; ++ni) {
            const int t = t0b + ni * 16 + rlo;
            union { ushort4 u; __hip_bfloat16 hh[4]; } pk;
            pk.hh[0] = __float2bfloat16(acc[mi][ni][0]);
            pk.hh[1] = __float2bfloat16(acc[mi][ni][1]);
            pk.hh[2] = __float2bfloat16(acc[mi][ni][2]);
            pk.hh[3] = __float2bfloat16(acc[mi][ni][3]);
            *(ushort4*)(fb + (((size_t)(bc * TFR + t)) << 9) + nbase) = pk.u;
        }
    }
}

// ---------------------------------------------------------------------------
// Kernel 3: overlap-add + envelope normalize + the k=512 DC term (R5-R10-
//   verified).  W'[n][512] = wnd[n]*(1/512)*(-1)^n; contrib = that * re(X[256,t]).
// ---------------------------------------------------------------------------
__global__ __launch_bounds__(256) void k_ola(
    const __hip_bfloat16* __restrict__ frames,
    const float* __restrict__ wnd,
    const float* __restrict__ X,
    float* __restrict__ out)
{
    const int bc = blockIdx.y;
    const int o  = (blockIdx.x * 256 + threadIdx.x) * 4;
    if (o >= OUTLEN) return;
    const int s   = o + SPAD;
    const int tb_ = s >> 7;
    const int nb  = s & (HOPSZ - 1);
    const unsigned short* fb = (const unsigned short*)frames + (size_t)bc * TFR * NFFT;
    const float* Xre = X + (((size_t)bc * FBINS + 256) * TFR) * 2;  // re at [2t]
    const float sA = ((nb & 1) ? -1.0f : 1.0f) * (1.0f / 512.0f);
    float y0 = 0.f, y1 = 0.f, y2 = 0.f, y3 = 0.f;
    float e0 = 0.f, e1 = 0.f, e2 = 0.f, e3 = 0.f;
    #pragma unroll
    for (int r = 0; r < 4; ++r) {
        const int t = tb_ - r;
        if ((unsigned)t > (unsigned)(TFR - 1)) continue;
        const int n = nb + (r << 7);
        ushort4 v = *(const ushort4*)(fb + (size_t)t * NFFT + n);
        float4  wv = *(const float4*)(wnd + n);
        const float c = sA * Xre[2 * t];
        y0 += bf2f(v.x) + c * wv.x; e0 += wv.x * wv.x;
        y1 += bf2f(v.y) - c * wv.y; e1 += wv.y * wv.y;
        y2 += bf2f(v.z) + c * wv.z; e2 += wv.z * wv.z;
        y3 += bf2f(v.w) - c * wv.w; e3 += wv.w * wv.w;
    }
    float4 res = make_float4(y0 / e0, y1 / e1, y2 / e2, y3 / e3);
    *(float4*)(out + (size_t)bc * OUTLEN + o) = res;
}

// ---------------------------------------------------------------------------
extern "C" void kernel_launch(void* const* d_in, const int* in_sizes, int n_in,
                              void* d_out, int out_size, void* d_ws, size_t ws_size,
                              hipStream_t stream) {
    (void)in_sizes; (void)n_in; (void)out_size; (void)ws_size;
    const float* X   = (const float*)d_in[0];
    const float* wnd = (const float*)d_in[1];
    float* out = (float*)d_out;

    uint4* Wf = (uint4*)d_ws;                                            // 544 KB
    __hip_bfloat16* frames = (__hip_bfloat16*)((char*)d_ws + (1 << 20)); // 64 MB

    k_wgen<<<136, 256, 0, stream>>>(wnd, Wf);
    k_mm<<<2048, 256, 0, stream>>>(X, Wf, frames);
    k_ola<<<dim3((OUTLEN / 4 + 255) / 256, NBC), 256, 0, stream>>>(frames, wnd, X, out);
}

// Round 12
// 79.385 us; speedup vs baseline: 1.0463x; 1.0463x over previous
//
#include <hip/hip_runtime.h>
#include <hip/hip_bf16.h>

#define NFFT    512
#define HOPSZ   128
#define FBINS   257
#define TFR     2048
#define NBC     32            // B*C
#define OUTLEN  262016        // (T-1)*HOP
#define SPAD    256           // n_fft/2 (center trim)
#define NPANEL  34            // ceil over stride-61 panels
#define PSTR    61            // panel stride in frames (64-tile, 3 overlap)
#define FROW    532           // F row stride in bf16 (1064 B, odd-word: ~2-way)

typedef __bf16 bf16x8 __attribute__((ext_vector_type(8)));
typedef float  f32x4  __attribute__((ext_vector_type(4)));

static __device__ __forceinline__ float bf2f(unsigned short u) {
    union { unsigned int i; float f; } x; x.i = (unsigned int)u << 16; return x.f;
}

__device__ __forceinline__ void gld_lds16(const void* g, void* l) {
    __builtin_amdgcn_global_load_lds(
        (const __attribute__((address_space(1))) unsigned int*)g,
        (__attribute__((address_space(3))) unsigned int*)l, 16, 0, 0);
}

// ---------------------------------------------------------------------------
// Kernel 1: W' in MFMA A-fragment order (verified R2-R11).
//   Wf[(ks*32 + rt)*64 + lane]: 8 bf16, elem j:
//     n = rt*16 + (lane&15),  k = ks*32 + 4*(lane>>4) + (j&3) + 16*(j>>2)
// ---------------------------------------------------------------------------
__global__ __launch_bounds__(256) void k_wgen(const float* __restrict__ wnd,
                                              uint4* __restrict__ Wf) {
    const int gid  = blockIdx.x * 256 + threadIdx.x;   // < 34816
    const int lane = gid & 63;
    const int rt   = (gid >> 6) & 31;
    const int ks   = gid >> 11;
    const int n    = rt * 16 + (lane & 15);
    const int kb   = ks * 32 + ((lane >> 4) << 2);
    const float wn = wnd[n] * (1.0f / 512.0f);
    union { uint4 u; unsigned short h[8]; } o;
    #pragma unroll
    for (int j = 0; j < 8; ++j) {
        const int k = kb + (j & 3) + 16 * (j >> 2);
        float val = 0.0f;
        if (k < 2 * FBINS) {
            const int f = k >> 1;
            const bool edge = (f == 0) || (f == 256);
            const float cf = edge ? 1.0f : 2.0f;
            const int m = (f * n) & (NFFT - 1);
            const float ang = (float)m * 0.01227184630308513f; // 2*pi/512
            float s, c;
            __sincosf(ang, &s, &c);
            val = (k & 1) ? (edge ? 0.0f : -cf * wn * s) : (cf * wn * c);
        }
        __hip_bfloat16 hb = __float2bfloat16(val);
        o.h[j] = *(unsigned short*)&hb;
    }
    Wf[gid] = o.u;
}

// ---------------------------------------------------------------------------
// Kernel 2 (FUSED): GEMM (R7 core verbatim) + in-LDS overlap-add.
//   1088 blocks = 32 bc x 34 panels; panel p -> frames [61p, 61p+64).
//   Stride-61 tiling: block's own 64 frames fully determine outputs
//   o in [128tp+128, 128tp+7936) -> exact tiling, no halo exchange,
//   +6% redundant MFMA. frames intermediate ELIMINATED (saves 128 MB
//   of HBM traffic + the k_ola kernel).
//   LDS union (72 KB, 2 blocks/CU): GEMM staging {Ab 64K | Bb 8K} then
//   post phase {F[64][FROW] bf16 67.8K | XreL 256B | wL 2K}.
// ---------------------------------------------------------------------------
__global__ __launch_bounds__(512, 4) void k_fused(
    const float* __restrict__ X,
    const uint4* __restrict__ Wf,
    const float* __restrict__ wnd,
    float* __restrict__ out)
{
    __shared__ __align__(16) char smem[73728];
    uint4* Ab  = (uint4*)smem;                        // [2][32][64] 64 KB
    uint4* Bb4 = (uint4*)(smem + 65536);              // [2][4][64]   8 KB
    unsigned int* BbU = (unsigned int*)(smem + 65536);
    float* XreL = (float*)(smem + 68096);             // 64 floats
    float* wL   = (float*)(smem + 68352);             // 512 floats

    const int tid  = threadIdx.x;
    const int lane = tid & 63;
    const int w    = tid >> 6;        // wave -> rows [64w, +64)
    const int q    = lane >> 4;
    const int rlo  = lane & 15;

    const int bid = blockIdx.x;       // 1088 = 8 XCD-chunks of 136
    const int id  = (bid & 7) * 136 + (bid >> 3);
    const int panel = id % NPANEL;
    const int bc    = id / NPANEL;    // 0..31
    const int tp    = panel * PSTR;   // frame base (arbitrary, not pow2)

    const float2* __restrict__ X2 = (const float2*)X + (size_t)bc * FBINS * TFR;

    // B staging roles (R7-verified): sf = f_local 0..31, st = t-slot 0..15
    const int sf  = tid >> 4;
    const int st  = tid & 15;
    const int r2  = (2 * sf) & 31;
    const int skk = sf >> 4;
    const int sq  = (r2 & 15) >> 2;
    const int sj  = ((r2 & 2) >> 1) + (((r2 >> 4) & 1) << 1);

    f32x4 acc[4][4] = {};

    // ================= GEMM phase (R7 core) =================
    for (int ks = 0; ks < 8; ++ks) {
        __syncthreads();
        // --- B loads first (4x 8B; t clamped for last panel) ---
        float2 xv[4];
        #pragma unroll
        for (int d = 0; d < 4; ++d) {
            int t = tp + st + (d << 4);
            t = (t < TFR) ? t : (TFR - 1);             // garbage rows masked in OLA
            xv[d] = X2[(size_t)(ks * 32 + sf) * TFR + t];
        }
        // --- A: 8x global_load_lds dwordx4 (2 slabs of 32 KB) ---
        #pragma unroll
        for (int s = 0; s < 2; ++s) {
            const uint4* src = Wf + (size_t)(2 * ks + s) * 2048;
            uint4* dst = Ab + s * 2048;
            #pragma unroll
            for (int r = 0; r < 4; ++r)
                gld_lds16(src + r * 512 + tid, dst + r * 512 + tid);
        }
        // --- B pack + LDS writes (R7-verified mapping) ---
        #pragma unroll
        for (int d = 0; d < 4; ++d) {
            union { unsigned int u; __hip_bfloat16 h[2]; } p;
            p.h[0] = __float2bfloat16(xv[d].x);
            p.h[1] = __float2bfloat16(xv[d].y);
            BbU[(((((skk << 2) + sq) << 6) + st + (d << 4)) << 2) + sj] = p.u;
        }
        __syncthreads();
        // --- compute: 32 MFMA / wave ---
        #pragma unroll
        for (int kk = 0; kk < 2; ++kk) {
            uint4 a[4], b[4];
            #pragma unroll
            for (int ni = 0; ni < 4; ++ni) b[ni] = Bb4[(kk * 4 + q) * 64 + ni * 16 + rlo];
            #pragma unroll
            for (int mi = 0; mi < 4; ++mi) a[mi] = Ab[(kk * 32 + 4 * w + mi) * 64 + lane];
            #pragma unroll
            for (int mi = 0; mi < 4; ++mi)
                #pragma unroll
                for (int ni = 0; ni < 4; ++ni)
                    acc[mi][ni] = __builtin_amdgcn_mfma_f32_16x16x32_bf16(
                        __builtin_bit_cast(bf16x8, a[mi]),
                        __builtin_bit_cast(bf16x8, b[ni]), acc[mi][ni], 0, 0, 0);
        }
    }

    // ================= acc -> F (LDS), stage Xre/wnd =================
    __syncthreads();                  // all staging reads done before union reuse
    #pragma unroll
    for (int mi = 0; mi < 4; ++mi) {
        const int n = (w << 6) + (mi << 4) + (q << 2);
        #pragma unroll
        for (int ni = 0; ni < 4; ++ni) {
            const int lt = ni * 16 + rlo;              // frame t = tp + lt (C/D col)
            union { ushort4 u; __hip_bfloat16 hh[4]; } pk;
            pk.hh[0] = __float2bfloat16(acc[mi][ni][0]);
            pk.hh[1] = __float2bfloat16(acc[mi][ni][1]);
            pk.hh[2] = __float2bfloat16(acc[mi][ni][2]);
            pk.hh[3] = __float2bfloat16(acc[mi][ni][3]);
            *(ushort4*)((unsigned short*)(smem + lt * (FROW * 2)) + n) = pk.u;
        }
    }
    if (tid < 64) {                   // DC term source: re(X[256, tp+lt])
        int t = tp + tid;
        t = (t < TFR) ? t : (TFR - 1);
        XreL[tid] = X2[(size_t)256 * TFR + t].x;
    }
    wL[tid] = wnd[tid];               // 512 threads, 512 floats
    __syncthreads();

    // ================= OLA + envelope normalize (k_ola math, R5-R11) =====
    const int olo = (panel == 0) ? 0 : tp * 128 + 128;
    const int ohi = (panel == NPANEL - 1) ? OUTLEN : tp * 128 + 7936;
    float* outb = out + (size_t)bc * OUTLEN;
    for (int o = olo + tid; o < ohi; o += 512) {
        const int s  = o + SPAD;
        const int tb = s >> 7;
        const int nb = s & (HOPSZ - 1);
        const float sg = (s & 1) ? (-1.0f / 512.0f) : (1.0f / 512.0f);
        float y = 0.f, e = 0.f;
        #pragma unroll
        for (int r = 0; r < 4; ++r) {
            const int t  = tb - r;
            const int lt = t - tp;
            if ((unsigned)lt >= 64u || (unsigned)t >= (unsigned)TFR) continue;
            const int n = nb + (r << 7);
            const float wv = wL[n];
            const float fv = bf2f(*((const unsigned short*)(smem + lt * (FROW * 2)) + n));
            y += fv + sg * XreL[lt] * wv;
            e += wv * wv;
        }
        outb[o] = y / e;
    }
}

// ---------------------------------------------------------------------------
extern "C" void kernel_launch(void* const* d_in, const int* in_sizes, int n_in,
                              void* d_out, int out_size, void* d_ws, size_t ws_size,
                              hipStream_t stream) {
    (void)in_sizes; (void)n_in; (void)out_size; (void)ws_size;
    const float* X   = (const float*)d_in[0];
    const float* wnd = (const float*)d_in[1];
    float* out = (float*)d_out;

    uint4* Wf = (uint4*)d_ws;                                            // 544 KB

    k_wgen<<<136, 256, 0, stream>>>(wnd, Wf);
    k_fused<<<NBC * NPANEL, 512, 0, stream>>>(X, Wf, wnd, out);
}